// Round 6
// baseline (757.787 us; speedup 1.0000x reference)
//
#include <hip/hip_runtime.h>
#include <cstdint>
#include <cstddef>
#include <math.h>

#define M_ROWS 16384
#define N_COLS 1000
#define N_PAD  1024
#define K_DIM  4096
#define NUM_TTA 64
#define KEPT 6
#define BATCH 256
#define CHUNK_MAX 16384
#define NKT (K_DIM / 32)       // 128 K-tiles of 32

typedef __attribute__((ext_vector_type(8))) short short8;
typedef __attribute__((ext_vector_type(4))) float v4f;

#define GL_LDS16(g, l)                                                        \
    __builtin_amdgcn_global_load_lds(                                         \
        (const __attribute__((address_space(1))) unsigned int*)(g),           \
        (__attribute__((address_space(3))) unsigned int*)(l), 16, 0, 0)

// ---- RNE bf16 split via HW cvt: x = hi + lo (+ ~2^-18 rel) ----
__device__ __forceinline__ void split2(float x, unsigned short& h, unsigned short& l) {
    const __bf16 hb = (__bf16)x;
    const float hf  = (float)hb;
    const __bf16 lb = (__bf16)(x - hf);
    h = __builtin_bit_cast(unsigned short, hb);
    l = __builtin_bit_cast(unsigned short, lb);
}

// 8 floats -> 8 hi bf16 + 8 lo bf16
__device__ __forceinline__ void split8(const float4& a, const float4& b,
                                       short8& hv, short8& lv) {
    unsigned short h, l;
    split2(a.x, h, l); hv[0] = (short)h; lv[0] = (short)l;
    split2(a.y, h, l); hv[1] = (short)h; lv[1] = (short)l;
    split2(a.z, h, l); hv[2] = (short)h; lv[2] = (short)l;
    split2(a.w, h, l); hv[3] = (short)h; lv[3] = (short)l;
    split2(b.x, h, l); hv[4] = (short)h; lv[4] = (short)l;
    split2(b.y, h, l); hv[5] = (short)h; lv[5] = (short)l;
    split2(b.z, h, l); hv[6] = (short)h; lv[6] = (short)l;
    split2(b.w, h, l); hv[7] = (short)h; lv[7] = (short)l;
}

// ---------------- W: transpose 4096x1000 -> [n][k] 1024x4096, split ----------------
__global__ __launch_bounds__(1024)
void split_w(const float* __restrict__ W, unsigned short* __restrict__ Wh,
             unsigned short* __restrict__ Wl)
{
    __shared__ float tile[32][33];
    const int k0 = blockIdx.x * 32, n0 = blockIdx.y * 32;
    const int tx = threadIdx.x, ty = threadIdx.y;
    const int n = n0 + tx, k = k0 + ty;
    tile[ty][tx] = (n < N_COLS) ? W[(size_t)k * N_COLS + n] : 0.f;
    __syncthreads();
    const float w = tile[tx][ty];           // = W[k0+tx][n0+ty]
    unsigned short h, l;
    split2(w, h, l);
    const size_t o = (size_t)(n0 + ty) * K_DIM + k0 + tx;
    Wh[o] = h; Wl[o] = l;
}

// ------------- GEMM: logits = X @ Wt^T + b via bf16 split-2 MFMA -------------
// 128x128 tile, 256 thr = 4 waves (2m x 2n), wave = 64x64 out, BK=32 dbuf.
// LDS = 64 KiB -> TWO blocks co-resident per CU.  The two blocks are never
// barrier-synced with each other, so one block's post-barrier ds_read burst
// overlaps the other block's MFMA phase (and each block's tile-top vmcnt(0)
// stall is covered by the other) -- breaking the read-phase/MFMA-phase
// serialization the single-resident-block 256^2 layout suffered.
// Read:FLOP ratio unchanged (16 b128 : 48 MFMA per wave-tile).
__global__ __launch_bounds__(256, 2)
void gemm_mfma(const float* __restrict__ X,
               const unsigned short* __restrict__ Bh_, const unsigned short* __restrict__ Bl_,
               const float* __restrict__ bias, float* __restrict__ logits,
               int m_tiles)
{
    // per buffer (32KB): Ah[0,8K) Al[8K,16K) Bh[16K,24K) Bl[24K,32K)
    __shared__ __attribute__((aligned(16))) char smem[2 * 32768];

    const int t    = threadIdx.x;
    const int lane = t & 63;
    const int wave = t >> 6;           // 0..3
    const int wr   = wave >> 1;        // 0..1  m-half of tile
    const int wc   = wave & 1;         // 0..1  n-half of tile
    const int ml   = lane & 15;
    const int kh   = lane >> 4;        // k-slot (8 bf16 each)

    // ---- XCD swizzle: 8 consecutive same-XCD slots = all 8 n-tiles of one
    //      m-strip -> A strip fetched ~once per XCD L2. nwg = 8*m_tiles. ----
    const int bid  = blockIdx.x;
    const int xcd  = bid & 7;
    const int slot = bid >> 3;
    const int mt   = xcd * (m_tiles >> 3) + (slot >> 3);
    const int nt   = slot & 7;
    const int m0 = mt * 128, n0 = nt * 128;

    // ---- B staging (global_load_lds, pre-swizzled source), 2 issues/panel ----
    const int    schunk = (t & 3) ^ ((t >> 3) & 3);
    const size_t ro     = (size_t)(t >> 2) * (K_DIM * 2) + (size_t)schunk * 16;
    const char* gBh = (const char*)Bh_ + (size_t)n0 * (K_DIM * 2) + ro;
    const char* gBl = (const char*)Bl_ + (size_t)n0 * (K_DIM * 2) + ro;
    const size_t RSTEP = (size_t)64 * K_DIM * 2;   // +64 rows
    char* ldst = smem + t * 16;

    // ---- A staging (reg path): thread t covers row ar, 16-float half ahalf ----
    const int ar    = t >> 1;          // 0..127
    const int ahalf = t & 1;           // k 0-15 or 16-31 within tile
    const float* gA = X + (size_t)(m0 + ar) * K_DIM + ahalf * 16;
    const int sig = (ar >> 1) & 3;     // row swizzle key (matches reader)
    const int s0  = (ahalf * 2) ^ sig;
    const int s1  = (ahalf * 2 + 1) ^ sig;
    const int aw0 = ar * 64 + (s0 << 4);   // LDS byte off in A panel, floats 0-7
    const int aw1 = ar * 64 + (s1 << 4);   // floats 8-15

    // ---- per-lane LDS read bases (bytes within one 8KB mat panel) ----
    const int swz = ((kh ^ (ml >> 1)) & 3) << 4;
    const int lbA = wr * 4096 + ml * 64 + swz;
    const int lbB = wc * 4096 + ml * 64 + swz;

    v4f acc[4][4];
#pragma unroll
    for (int i = 0; i < 4; ++i)
#pragma unroll
        for (int j = 0; j < 4; ++j) acc[i][j] = (v4f){0.f, 0.f, 0.f, 0.f};

#define FRAG(P) (*(const short8*)(smem + (P)))

    short8 ah[4], al[4], bh[4], bl[4];

    // ---------------- prologue: stage K-tile 0 into buf 0 ----------------
    {
        const float4 fa = *(const float4*)(gA);
        const float4 fb = *(const float4*)(gA + 4);
        const float4 fc = *(const float4*)(gA + 8);
        const float4 fd = *(const float4*)(gA + 12);
        GL_LDS16(gBh,         ldst + 16384);
        GL_LDS16(gBh + RSTEP, ldst + 20480);
        GL_LDS16(gBl,         ldst + 24576);
        GL_LDS16(gBl + RSTEP, ldst + 28672);
        short8 hv, lv;
        split8(fa, fb, hv, lv);
        *(short8*)(smem + aw0) = hv;
        *(short8*)(smem + 8192 + aw0) = lv;
        split8(fc, fd, hv, lv);
        *(short8*)(smem + aw1) = hv;
        *(short8*)(smem + 8192 + aw1) = lv;
    }
    __syncthreads();

#define TILE_BODY(KT, RB) do {                                                \
    const int B0 = (RB) * 32768;                                              \
    const int B1 = ((RB) ^ 1) * 32768;                                        \
    asm volatile("s_waitcnt vmcnt(0) lgkmcnt(0)" ::: "memory");               \
    __builtin_amdgcn_s_barrier();                                             \
    __builtin_amdgcn_sched_barrier(0);                                        \
    const bool pf = (KT) + 1 < NKT;                                           \
    float4 fa, fb, fc, fd;                                                    \
    if (pf) {   /* issue ALL of next tile's loads at tile top */              \
        const float* ga_ = gA + ((KT) + 1) * 32;                              \
        fa = *(const float4*)(ga_);                                           \
        fb = *(const float4*)(ga_ + 4);                                       \
        fc = *(const float4*)(ga_ + 8);                                       \
        fd = *(const float4*)(ga_ + 12);                                      \
        const int kb_ = ((KT) + 1) * 64;                                      \
        GL_LDS16(gBh + kb_,         ldst + B1 + 16384);                       \
        GL_LDS16(gBh + RSTEP + kb_, ldst + B1 + 20480);                       \
        GL_LDS16(gBl + kb_,         ldst + B1 + 24576);                       \
        GL_LDS16(gBl + RSTEP + kb_, ldst + B1 + 28672);                       \
    }                                                                         \
    /* ---- 16 frag reads ---- */                                             \
    _Pragma("unroll")                                                         \
    for (int nf = 0; nf < 4; ++nf) {                                          \
        bh[nf] = FRAG(B0 + 16384 + nf * 1024 + lbB);                          \
        bl[nf] = FRAG(B0 + 24576 + nf * 1024 + lbB);                          \
    }                                                                         \
    _Pragma("unroll")                                                         \
    for (int mf = 0; mf < 4; ++mf) {                                          \
        ah[mf] = FRAG(B0 +        mf * 1024 + lbA);                           \
        al[mf] = FRAG(B0 + 8192 + mf * 1024 + lbA);                           \
    }                                                                         \
    /* ---- 48 MFMA: 3 passes x 16 independent accs ---- */                   \
    __builtin_amdgcn_s_setprio(1);                                            \
    _Pragma("unroll")                                                         \
    for (int mf = 0; mf < 4; ++mf)                                            \
        _Pragma("unroll")                                                     \
        for (int nf = 0; nf < 4; ++nf)                                        \
            acc[mf][nf] = __builtin_amdgcn_mfma_f32_16x16x32_bf16(ah[mf], bl[nf], acc[mf][nf], 0, 0, 0); \
    _Pragma("unroll")                                                         \
    for (int mf = 0; mf < 4; ++mf)                                            \
        _Pragma("unroll")                                                     \
        for (int nf = 0; nf < 4; ++nf)                                        \
            acc[mf][nf] = __builtin_amdgcn_mfma_f32_16x16x32_bf16(al[mf], bh[nf], acc[mf][nf], 0, 0, 0); \
    _Pragma("unroll")                                                         \
    for (int mf = 0; mf < 4; ++mf)                                            \
        _Pragma("unroll")                                                     \
        for (int nf = 0; nf < 4; ++nf)                                        \
            acc[mf][nf] = __builtin_amdgcn_mfma_f32_16x16x32_bf16(ah[mf], bh[nf], acc[mf][nf], 0, 0, 0); \
    __builtin_amdgcn_s_setprio(0);                                            \
    if (pf) {   /* split -> swizzled ds_write into next buffer */             \
        short8 hv, lv;                                                        \
        split8(fa, fb, hv, lv);                                               \
        *(short8*)(smem + B1 + aw0) = hv;                                     \
        *(short8*)(smem + B1 + 8192 + aw0) = lv;                              \
        split8(fc, fd, hv, lv);                                               \
        *(short8*)(smem + B1 + aw1) = hv;                                     \
        *(short8*)(smem + B1 + 8192 + aw1) = lv;                              \
    }                                                                         \
} while (0)

#pragma unroll 1
    for (int kt = 0; kt < NKT; kt += 2) {
        TILE_BODY(kt, 0);
        TILE_BODY(kt + 1, 1);
    }

    // epilogue: C/D layout col = lane&15, row = (lane>>4)*4 + reg  [m89/m91]
#pragma unroll
    for (int mi = 0; mi < 4; ++mi) {
        const int rbase = m0 + wr * 64 + mi * 16 + kh * 4;
#pragma unroll
        for (int ni = 0; ni < 4; ++ni) {
            const int col = n0 + wc * 64 + ni * 16 + ml;
            if (col < N_COLS) {
                const float bv = bias[col];
#pragma unroll
                for (int r = 0; r < 4; ++r)
                    logits[(size_t)(rbase + r) * N_COLS + col] = acc[mi][ni][r] + bv;
            }
        }
    }
#undef TILE_BODY
#undef FRAG
}

// ---- inline f64 exp for d <= 0: rndne + 2-part ln2 + degree-12 Horner ----
__device__ __forceinline__ double exp_neg(double d) {
    if (d < -700.0) return 0.0;
    const double kd = rint(d * 1.4426950408889634074);
    double r = fma(-kd, 6.93147180369123816490e-01, d);
    r = fma(-kd, 1.90821492927058770002e-10, r);
    double p = 2.08767569878680989792e-09;      // 1/12!
    p = fma(p, r, 2.50521083854417187751e-08);  // 1/11!
    p = fma(p, r, 2.75573192239858906526e-07);  // 1/10!
    p = fma(p, r, 2.75573192239858925110e-06);  // 1/9!
    p = fma(p, r, 2.48015873015873015873e-05);  // 1/8!
    p = fma(p, r, 1.98412698412698412526e-04);  // 1/7!
    p = fma(p, r, 1.38888888888888894069e-03);  // 1/6!
    p = fma(p, r, 8.33333333333333321769e-03);  // 1/5!
    p = fma(p, r, 4.16666666666666643537e-02);  // 1/4!
    p = fma(p, r, 1.66666666666666657415e-01);  // 1/3!
    p = fma(p, r, 5.0e-01);
    p = fma(p, r, 1.0);
    p = fma(p, r, 1.0);
    const long long k = (long long)kd;
    return p * __longlong_as_double((1023LL + k) << 52);
}

// ------------- per-view softmax stats: entropy (f64 accum) + argmax -------------
// 1 wave per row, 4 rows per block; row held in 16 VGPR; shuffle reductions.
__global__ __launch_bounds__(256)
void row_stats(const float* __restrict__ logits, double* __restrict__ ent,
               int* __restrict__ votes, int v_base)
{
    const int lane = threadIdx.x & 63;
    const int wave = threadIdx.x >> 6;
    const int row  = blockIdx.x * 4 + wave;
    const float* rp = logits + (size_t)row * N_COLS;

    float v[16];
    float bv = -3.0e38f; int bi = 0;
#pragma unroll
    for (int j = 0; j < 16; ++j) {
        const int c = j * 64 + lane;
        const float x = (c < N_COLS) ? rp[c] : -3.0e38f;
        v[j] = x;
        if (x > bv) { bv = x; bi = c; }
    }
#pragma unroll
    for (int s = 32; s > 0; s >>= 1) {
        const float ov = __shfl_xor(bv, s);
        const int   oi = __shfl_xor(bi, s);
        if (ov > bv || (ov == bv && oi < bi)) { bv = ov; bi = oi; }
    }
    const float mx = bv;
    const int amax = bi;

    double S = 0.0, T = 0.0;
#pragma unroll
    for (int j = 0; j < 16; ++j) {
        const int c = j * 64 + lane;
        if (c < N_COLS) {
            const float d = v[j] - mx;
            const double e = exp_neg((double)d);
            S += e; T += e * (double)d;
        }
    }
#pragma unroll
    for (int s = 32; s > 0; s >>= 1) {
        S += __shfl_xor(S, s);
        T += __shfl_xor(T, s);
    }
    if (lane == 0) {
        ent[v_base + row]   = log(S) - T / S;
        votes[v_base + row] = amax;
    }
}

// ------------- per-batch voting: stable sort by entropy, tie loop -------------
__global__ __launch_bounds__(64)
void vote_kernel(const double* __restrict__ ent, const int* __restrict__ votes,
                 float* __restrict__ out)
{
    __shared__ double e[NUM_TTA];
    __shared__ int    sv[NUM_TTA];
    __shared__ float  counts[N_COLS];

    const int b = blockIdx.x;
    const int t = threadIdx.x;

    e[t] = ent[b * NUM_TTA + t];
    const int myv = votes[b * NUM_TTA + t];
    for (int c = t; c < N_COLS; c += NUM_TTA) counts[c] = 0.f;
    __syncthreads();

    const double et = e[t];
    int rank = 0;
#pragma unroll
    for (int i = 0; i < NUM_TTA; ++i) {
        const double ei = e[i];
        rank += (ei < et) || (ei == et && i < t);
    }
    sv[rank] = myv;
    __syncthreads();

    if (t == 0) {
        for (int j = 0; j < KEPT; ++j) counts[sv[j]] += 1.f;
        float Mv = 0.f; int Tc = 0;
        for (int j = 0; j < KEPT; ++j) {
            const int c = sv[j];
            bool dup = false;
            for (int q = 0; q < j; ++q) dup = dup || (sv[q] == c);
            if (dup) continue;
            const float cv = counts[c];
            if (cv > Mv) { Mv = cv; Tc = 1; }
            else if (cv == Mv) { Tc += 1; }
        }
        for (int i = 0; i < NUM_TTA - KEPT; ++i) {
            if (Tc <= 1) break;
            const int c = sv[KEPT + i];
            const float oldc = counts[c];
            counts[c] = oldc + 1.f;
            if (oldc == Mv)            { Mv += 1.f; Tc = 1; }
            else if (oldc + 1.f == Mv) { Tc += 1; }
        }
    }
    __syncthreads();

    const size_t o0 = (size_t)b * N_COLS;
    for (int c = t; c < N_COLS; c += NUM_TTA)
        out[o0 + c] = logf(counts[c] * (1.f / 64.f) + 1e-8f);
}

// -------------------------------- launch --------------------------------
extern "C" void kernel_launch(void* const* d_in, const int* in_sizes, int n_in,
                              void* d_out, int out_size, void* d_ws, size_t ws_size,
                              hipStream_t stream) {
    const float* x    = (const float*)d_in[0];
    const float* Wm   = (const float*)d_in[1];
    const float* bias = (const float*)d_in[2];
    float* out = (float*)d_out;

    // ws layout: ent f64[16384] | votes i32[16384] | Wh,Wl bf16[1024*4096]
    //            | per-chunk logits f32[R*1000]   (A split fused in GEMM)
    char* p = (char*)d_ws;
    double* ent  = (double*)p;                     p += (size_t)M_ROWS * 8;
    int*   votes = (int*)p;                        p += (size_t)M_ROWS * 4;
    unsigned short* Wh = (unsigned short*)p;       p += (size_t)N_PAD * K_DIM * 2;
    unsigned short* Wl = (unsigned short*)p;       p += (size_t)N_PAD * K_DIM * 2;
    const size_t base = (size_t)(p - (char*)d_ws);

    // R: rows per chunk, multiple of 1024 so m_tiles (rows/128) is divisible by 8
    long long R = 0;
    if (ws_size > base) R = (long long)((ws_size - base) / (size_t)4000);
    R = (R / 1024) * 1024;
    if (R > CHUNK_MAX) R = CHUNK_MAX;
    if (R < 1024) R = 1024;

    float* logits = (float*)p;

    split_w<<<dim3(K_DIM / 32, N_PAD / 32), dim3(32, 32), 0, stream>>>(Wm, Wh, Wl);

    for (int m0 = 0; m0 < M_ROWS; m0 += (int)R) {
        const int rows = (int)(((long long)(M_ROWS - m0) < R) ? (M_ROWS - m0) : R);
        const int m_tiles = rows / 128;
        gemm_mfma<<<8 * m_tiles, 256, 0, stream>>>(
            x + (size_t)m0 * K_DIM, Wh, Wl, bias, logits, m_tiles);
        row_stats<<<rows / 4, 256, 0, stream>>>(logits, ent, votes, m0);
    }
    vote_kernel<<<BATCH, NUM_TTA, 0, stream>>>(ent, votes, out);
}

// Round 7
// 650.748 us; speedup vs baseline: 1.1645x; 1.1645x over previous
//
#include <hip/hip_runtime.h>
#include <cstdint>
#include <cstddef>
#include <math.h>

#define M_ROWS 16384
#define N_COLS 1000
#define N_PAD  1024
#define K_DIM  4096
#define NUM_TTA 64
#define KEPT 6
#define BATCH 256
#define CHUNK_MAX 16384
#define NKT (K_DIM / 32)       // 128 K-tiles of 32

typedef __attribute__((ext_vector_type(8))) short short8;
typedef __attribute__((ext_vector_type(4))) float v4f;

#define GL_LDS16(g, l)                                                        \
    __builtin_amdgcn_global_load_lds(                                         \
        (const __attribute__((address_space(1))) unsigned int*)(g),           \
        (__attribute__((address_space(3))) unsigned int*)(l), 16, 0, 0)

// ---- RNE bf16 split via HW cvt: x = hi + lo (+ ~2^-18 rel) ----
__device__ __forceinline__ void split2(float x, unsigned short& h, unsigned short& l) {
    const __bf16 hb = (__bf16)x;
    const float hf  = (float)hb;
    const __bf16 lb = (__bf16)(x - hf);
    h = __builtin_bit_cast(unsigned short, hb);
    l = __builtin_bit_cast(unsigned short, lb);
}

// 8 floats -> 8 hi bf16 + 8 lo bf16
__device__ __forceinline__ void split8(const float4& a, const float4& b,
                                       short8& hv, short8& lv) {
    unsigned short h, l;
    split2(a.x, h, l); hv[0] = (short)h; lv[0] = (short)l;
    split2(a.y, h, l); hv[1] = (short)h; lv[1] = (short)l;
    split2(a.z, h, l); hv[2] = (short)h; lv[2] = (short)l;
    split2(a.w, h, l); hv[3] = (short)h; lv[3] = (short)l;
    split2(b.x, h, l); hv[4] = (short)h; lv[4] = (short)l;
    split2(b.y, h, l); hv[5] = (short)h; lv[5] = (short)l;
    split2(b.z, h, l); hv[6] = (short)h; lv[6] = (short)l;
    split2(b.w, h, l); hv[7] = (short)h; lv[7] = (short)l;
}

// ---------------- W: transpose 4096x1000 -> [n][k] 1024x4096, split ----------------
__global__ __launch_bounds__(1024)
void split_w(const float* __restrict__ W, unsigned short* __restrict__ Wh,
             unsigned short* __restrict__ Wl)
{
    __shared__ float tile[32][33];
    const int k0 = blockIdx.x * 32, n0 = blockIdx.y * 32;
    const int tx = threadIdx.x, ty = threadIdx.y;
    const int n = n0 + tx, k = k0 + ty;
    tile[ty][tx] = (n < N_COLS) ? W[(size_t)k * N_COLS + n] : 0.f;
    __syncthreads();
    const float w = tile[tx][ty];           // = W[k0+tx][n0+ty]
    unsigned short h, l;
    split2(w, h, l);
    const size_t o = (size_t)(n0 + ty) * K_DIM + k0 + tx;
    Wh[o] = h; Wl[o] = l;
}

// ------------- GEMM: logits = X @ Wt^T + b via bf16 split-2 MFMA -------------
// 256x256 tile, 512 thr = 8 waves (2m x 4n), wave = 128x64 out, BK=32.
// Round-7 change: sched_barrier(0)-fenced read/MFMA SOFTWARE PIPELINE.
// Reads are split into small clusters consumed 1-2 MFMA-clusters later, so
// the compiler emits counted lgkmcnt and waves enter each MFMA cluster
// staggered by their LDS-port queue position -> port bursts hide under the
// previous cluster's MFMA instead of serializing (r2-r6 all measured
// port+MFMA as a SERIAL sum).  Per-acc MFMA chain order unchanged.
__global__ __launch_bounds__(512, 2)
void gemm_mfma(const float* __restrict__ X,
               const unsigned short* __restrict__ Bh_, const unsigned short* __restrict__ Bl_,
               const float* __restrict__ bias, float* __restrict__ logits,
               int m_tiles)
{
    __shared__ __attribute__((aligned(16))) char smem[2 * 4 * 16384];

    const int t    = threadIdx.x;
    const int lane = t & 63;
    const int wave = t >> 6;
    const int wr   = wave >> 2;        // 0..1  m-half of block tile
    const int wc   = wave & 3;         // 0..3  n-quarter
    const int ml   = lane & 15;
    const int kh   = lane >> 4;        // k-slot (8 bf16 each)

    // ---- XCD swizzle ----
    const int bid  = blockIdx.x;
    const int xcd  = bid & 7;
    const int slot = bid >> 3;
    const int mt   = xcd * (m_tiles >> 3) + (slot >> 2);
    const int nt   = slot & 3;
    const int m0 = mt * 256, n0 = nt * 256;

    // ---- B staging (global_load_lds, pre-swizzled source) ----
    const int    schunk = (t & 3) ^ ((t >> 3) & 3);
    const size_t ro     = (size_t)(t >> 2) * (K_DIM * 2) + (size_t)schunk * 16;
    const char* gBh = (const char*)Bh_ + (size_t)n0 * (K_DIM * 2) + ro;
    const char* gBl = (const char*)Bl_ + (size_t)n0 * (K_DIM * 2) + ro;
    char* ldst = smem + t * 16;
    const size_t RSTEP = (size_t)128 * K_DIM * 2;   // +128 rows

    // ---- A staging (reg path): thread t covers row ar, 16-float half ahalf ----
    const int ar    = t >> 1;          // 0..255
    const int ahalf = t & 1;           // k 0-15 or 16-31 within tile
    const float* gA = X + (size_t)(m0 + ar) * K_DIM + ahalf * 16;
    const int sig = (ar >> 1) & 3;     // row swizzle key (matches reader)
    const int s0  = (ahalf * 2) ^ sig;
    const int s1  = (ahalf * 2 + 1) ^ sig;
    const int aw0 = ar * 64 + (s0 << 4);   // LDS byte off in A panel, floats 0-7
    const int aw1 = ar * 64 + (s1 << 4);   // floats 8-15

    // ---- per-lane LDS read bases (bytes within one 16KB mat panel) ----
    const int swz = ((kh ^ (ml >> 1)) & 3) << 4;
    const int lbA = wr * 8192 + ml * 64 + swz;
    const int lbB = wc * 4096 + ml * 64 + swz;

    v4f acc[8][4];
#pragma unroll
    for (int i = 0; i < 8; ++i)
#pragma unroll
        for (int j = 0; j < 4; ++j) acc[i][j] = (v4f){0.f, 0.f, 0.f, 0.f};

#define FRAG(P) (*(const short8*)(smem + (P)))
#define SB __builtin_amdgcn_sched_barrier(0)

    short8 ah[4], al[4], bh[4], bl[4];

    // ---------------- prologue: stage K-tile 0 into buf 0 ----------------
    {
        const float4 fa = *(const float4*)(gA);
        const float4 fb = *(const float4*)(gA + 4);
        const float4 fc = *(const float4*)(gA + 8);
        const float4 fd = *(const float4*)(gA + 12);
        GL_LDS16(gBh,         ldst + 32768);
        GL_LDS16(gBh + RSTEP, ldst + 40960);
        GL_LDS16(gBl,         ldst + 49152);
        GL_LDS16(gBl + RSTEP, ldst + 57344);
        short8 hv, lv;
        split8(fa, fb, hv, lv);
        *(short8*)(smem + aw0) = hv;
        *(short8*)(smem + 16384 + aw0) = lv;
        split8(fc, fd, hv, lv);
        *(short8*)(smem + aw1) = hv;
        *(short8*)(smem + 16384 + aw1) = lv;
    }
    __syncthreads();

// read one B n-quarter (2 reads)
#define RD_B(NF) do {                                                         \
    bh[NF] = FRAG(B0 + 32768 + (NF) * 1024 + lbB);                            \
    bl[NF] = FRAG(B0 + 49152 + (NF) * 1024 + lbB);                            \
} while (0)
// read one A m-frag pair from m-half HO (0 or 4096)
#define RD_A(MF, HO) do {                                                     \
    ah[MF] = FRAG(B0 + (HO) +         (MF) * 1024 + lbA);                     \
    al[MF] = FRAG(B0 + (HO) + 16384 + (MF) * 1024 + lbA);                     \
} while (0)
// m-half-0 cluster: one n-quarter across 4 m-frags (12 MFMA, per-acc order kept)
#define MCLN(NF) do {                                                         \
    __builtin_amdgcn_s_setprio(1);                                            \
    _Pragma("unroll")                                                         \
    for (int mf = 0; mf < 4; ++mf)                                            \
        acc[mf][NF] = __builtin_amdgcn_mfma_f32_16x16x32_bf16(ah[mf], bl[NF], acc[mf][NF], 0, 0, 0); \
    _Pragma("unroll")                                                         \
    for (int mf = 0; mf < 4; ++mf)                                            \
        acc[mf][NF] = __builtin_amdgcn_mfma_f32_16x16x32_bf16(al[mf], bh[NF], acc[mf][NF], 0, 0, 0); \
    _Pragma("unroll")                                                         \
    for (int mf = 0; mf < 4; ++mf)                                            \
        acc[mf][NF] = __builtin_amdgcn_mfma_f32_16x16x32_bf16(ah[mf], bh[NF], acc[mf][NF], 0, 0, 0); \
    __builtin_amdgcn_s_setprio(0);                                            \
} while (0)
// m-half-1 cluster: one m-frag across 4 n-quarters (12 MFMA, per-acc order kept)
#define MCLM(MF) do {                                                         \
    __builtin_amdgcn_s_setprio(1);                                            \
    _Pragma("unroll")                                                         \
    for (int nf = 0; nf < 4; ++nf)                                            \
        acc[4 + (MF)][nf] = __builtin_amdgcn_mfma_f32_16x16x32_bf16(ah[MF], bl[nf], acc[4 + (MF)][nf], 0, 0, 0); \
    _Pragma("unroll")                                                         \
    for (int nf = 0; nf < 4; ++nf)                                            \
        acc[4 + (MF)][nf] = __builtin_amdgcn_mfma_f32_16x16x32_bf16(al[MF], bh[nf], acc[4 + (MF)][nf], 0, 0, 0); \
    _Pragma("unroll")                                                         \
    for (int nf = 0; nf < 4; ++nf)                                            \
        acc[4 + (MF)][nf] = __builtin_amdgcn_mfma_f32_16x16x32_bf16(ah[MF], bh[nf], acc[4 + (MF)][nf], 0, 0, 0); \
    __builtin_amdgcn_s_setprio(0);                                            \
} while (0)

#define TILE_BODY(KT, RB) do {                                                \
    const int B0 = (RB) * 65536;                                              \
    const int B1 = ((RB) ^ 1) * 65536;                                        \
    asm volatile("s_waitcnt vmcnt(0) lgkmcnt(0)" ::: "memory");               \
    __builtin_amdgcn_s_barrier();                                             \
    SB;                                                                       \
    const bool pf = (KT) + 1 < NKT;                                           \
    float4 fa, fb;                                                            \
    if (pf) {   /* issue next tile's loads early: A 8 floats + B GL_LDS */    \
        const float* ga_ = gA + ((KT) + 1) * 32;                              \
        fa = *(const float4*)(ga_);                                           \
        fb = *(const float4*)(ga_ + 4);                                       \
        const int kb_ = ((KT) + 1) * 64;                                      \
        GL_LDS16(gBh + kb_,         ldst + B1 + 32768);                       \
        GL_LDS16(gBh + RSTEP + kb_, ldst + B1 + 40960);                       \
        GL_LDS16(gBl + kb_,         ldst + B1 + 49152);                       \
        GL_LDS16(gBl + RSTEP + kb_, ldst + B1 + 57344);                       \
    }                                                                         \
    /* ---- fenced read/MFMA pipeline, m-half 0 (nf-major clusters) ---- */   \
    RD_B(0);                                                                  \
    RD_A(0, 0); RD_A(1, 0); RD_A(2, 0); RD_A(3, 0);                           \
    RD_B(1);                 /* lookahead */                                  \
    SB;                                                                       \
    MCLN(0); SB;                                                              \
    RD_B(2); SB;                                                              \
    MCLN(1); SB;                                                              \
    RD_B(3); SB;                                                              \
    MCLN(2); SB;                                                              \
    MCLN(3); SB;                                                              \
    /* ---- m-half 1 (mf-major clusters); A reads WAR-pinned after use ---- */\
    RD_A(0, 4096); RD_A(1, 4096); SB;                                         \
    MCLM(0); SB;                                                              \
    if (pf) {   /* split floats 0-7 -> write; then load floats 8-15 */        \
        short8 hv, lv;                                                        \
        split8(fa, fb, hv, lv);                                               \
        *(short8*)(smem + B1 + aw0) = hv;                                     \
        *(short8*)(smem + B1 + 16384 + aw0) = lv;                             \
        const float* ga_ = gA + ((KT) + 1) * 32 + 8;                          \
        fa = *(const float4*)(ga_);                                           \
        fb = *(const float4*)(ga_ + 4);                                       \
    }                                                                         \
    SB;                                                                       \
    RD_A(2, 4096); SB;                                                        \
    MCLM(1); SB;                                                              \
    RD_A(3, 4096); SB;                                                        \
    MCLM(2); SB;                                                              \
    if (pf) {   /* split floats 8-15 -> write */                              \
        short8 hv, lv;                                                        \
        split8(fa, fb, hv, lv);                                               \
        *(short8*)(smem + B1 + aw1) = hv;                                     \
        *(short8*)(smem + B1 + 16384 + aw1) = lv;                             \
    }                                                                         \
    SB;                                                                       \
    MCLM(3);                                                                  \
} while (0)

#pragma unroll 1
    for (int kt = 0; kt < NKT; kt += 2) {
        TILE_BODY(kt, 0);
        TILE_BODY(kt + 1, 1);
    }

    // epilogue: C/D layout col = lane&15, row = (lane>>4)*4 + reg  [m89/m91]
#pragma unroll
    for (int mi = 0; mi < 8; ++mi) {
        const int rbase = m0 + wr * 128 + (mi >> 2) * 64 + (mi & 3) * 16 + kh * 4;
#pragma unroll
        for (int ni = 0; ni < 4; ++ni) {
            const int col = n0 + wc * 64 + ni * 16 + ml;
            if (col < N_COLS) {
                const float bv = bias[col];
#pragma unroll
                for (int r = 0; r < 4; ++r)
                    logits[(size_t)(rbase + r) * N_COLS + col] = acc[mi][ni][r] + bv;
            }
        }
    }
#undef TILE_BODY
#undef MCLM
#undef MCLN
#undef RD_A
#undef RD_B
#undef SB
#undef FRAG
}

// ---- inline f64 exp for d <= 0: rndne + 2-part ln2 + degree-12 Horner ----
__device__ __forceinline__ double exp_neg(double d) {
    if (d < -700.0) return 0.0;
    const double kd = rint(d * 1.4426950408889634074);
    double r = fma(-kd, 6.93147180369123816490e-01, d);
    r = fma(-kd, 1.90821492927058770002e-10, r);
    double p = 2.08767569878680989792e-09;      // 1/12!
    p = fma(p, r, 2.50521083854417187751e-08);  // 1/11!
    p = fma(p, r, 2.75573192239858906526e-07);  // 1/10!
    p = fma(p, r, 2.75573192239858925110e-06);  // 1/9!
    p = fma(p, r, 2.48015873015873015873e-05);  // 1/8!
    p = fma(p, r, 1.98412698412698412526e-04);  // 1/7!
    p = fma(p, r, 1.38888888888888894069e-03);  // 1/6!
    p = fma(p, r, 8.33333333333333321769e-03);  // 1/5!
    p = fma(p, r, 4.16666666666666643537e-02);  // 1/4!
    p = fma(p, r, 1.66666666666666657415e-01);  // 1/3!
    p = fma(p, r, 5.0e-01);
    p = fma(p, r, 1.0);
    p = fma(p, r, 1.0);
    const long long k = (long long)kd;
    return p * __longlong_as_double((1023LL + k) << 52);
}

// ------------- per-view softmax stats: entropy (f64 accum) + argmax -------------
// 1 wave per row, 4 rows per block; row held in 16 VGPR; shuffle reductions.
__global__ __launch_bounds__(256)
void row_stats(const float* __restrict__ logits, double* __restrict__ ent,
               int* __restrict__ votes, int v_base)
{
    const int lane = threadIdx.x & 63;
    const int wave = threadIdx.x >> 6;
    const int row  = blockIdx.x * 4 + wave;
    const float* rp = logits + (size_t)row * N_COLS;

    float v[16];
    float bv = -3.0e38f; int bi = 0;
#pragma unroll
    for (int j = 0; j < 16; ++j) {
        const int c = j * 64 + lane;
        const float x = (c < N_COLS) ? rp[c] : -3.0e38f;
        v[j] = x;
        if (x > bv) { bv = x; bi = c; }
    }
#pragma unroll
    for (int s = 32; s > 0; s >>= 1) {
        const float ov = __shfl_xor(bv, s);
        const int   oi = __shfl_xor(bi, s);
        if (ov > bv || (ov == bv && oi < bi)) { bv = ov; bi = oi; }
    }
    const float mx = bv;
    const int amax = bi;

    double S = 0.0, T = 0.0;
#pragma unroll
    for (int j = 0; j < 16; ++j) {
        const int c = j * 64 + lane;
        if (c < N_COLS) {
            const float d = v[j] - mx;
            const double e = exp_neg((double)d);
            S += e; T += e * (double)d;
        }
    }
#pragma unroll
    for (int s = 32; s > 0; s >>= 1) {
        S += __shfl_xor(S, s);
        T += __shfl_xor(T, s);
    }
    if (lane == 0) {
        ent[v_base + row]   = log(S) - T / S;
        votes[v_base + row] = amax;
    }
}

// ------------- per-batch voting: stable sort by entropy, tie loop -------------
__global__ __launch_bounds__(64)
void vote_kernel(const double* __restrict__ ent, const int* __restrict__ votes,
                 float* __restrict__ out)
{
    __shared__ double e[NUM_TTA];
    __shared__ int    sv[NUM_TTA];
    __shared__ float  counts[N_COLS];

    const int b = blockIdx.x;
    const int t = threadIdx.x;

    e[t] = ent[b * NUM_TTA + t];
    const int myv = votes[b * NUM_TTA + t];
    for (int c = t; c < N_COLS; c += NUM_TTA) counts[c] = 0.f;
    __syncthreads();

    const double et = e[t];
    int rank = 0;
#pragma unroll
    for (int i = 0; i < NUM_TTA; ++i) {
        const double ei = e[i];
        rank += (ei < et) || (ei == et && i < t);
    }
    sv[rank] = myv;
    __syncthreads();

    if (t == 0) {
        for (int j = 0; j < KEPT; ++j) counts[sv[j]] += 1.f;
        float Mv = 0.f; int Tc = 0;
        for (int j = 0; j < KEPT; ++j) {
            const int c = sv[j];
            bool dup = false;
            for (int q = 0; q < j; ++q) dup = dup || (sv[q] == c);
            if (dup) continue;
            const float cv = counts[c];
            if (cv > Mv) { Mv = cv; Tc = 1; }
            else if (cv == Mv) { Tc += 1; }
        }
        for (int i = 0; i < NUM_TTA - KEPT; ++i) {
            if (Tc <= 1) break;
            const int c = sv[KEPT + i];
            const float oldc = counts[c];
            counts[c] = oldc + 1.f;
            if (oldc == Mv)            { Mv += 1.f; Tc = 1; }
            else if (oldc + 1.f == Mv) { Tc += 1; }
        }
    }
    __syncthreads();

    const size_t o0 = (size_t)b * N_COLS;
    for (int c = t; c < N_COLS; c += NUM_TTA)
        out[o0 + c] = logf(counts[c] * (1.f / 64.f) + 1e-8f);
}

// -------------------------------- launch --------------------------------
extern "C" void kernel_launch(void* const* d_in, const int* in_sizes, int n_in,
                              void* d_out, int out_size, void* d_ws, size_t ws_size,
                              hipStream_t stream) {
    const float* x    = (const float*)d_in[0];
    const float* Wm   = (const float*)d_in[1];
    const float* bias = (const float*)d_in[2];
    float* out = (float*)d_out;

    // ws layout: ent f64[16384] | votes i32[16384] | Wh,Wl bf16[1024*4096]
    //            | per-chunk logits f32[R*1000]   (A split fused in GEMM)
    char* p = (char*)d_ws;
    double* ent  = (double*)p;                     p += (size_t)M_ROWS * 8;
    int*   votes = (int*)p;                        p += (size_t)M_ROWS * 4;
    unsigned short* Wh = (unsigned short*)p;       p += (size_t)N_PAD * K_DIM * 2;
    unsigned short* Wl = (unsigned short*)p;       p += (size_t)N_PAD * K_DIM * 2;
    const size_t base = (size_t)(p - (char*)d_ws);

    // R: rows per chunk, multiple of 2048 so m_tiles (rows/256) is divisible by 8
    long long R = 0;
    if (ws_size > base) R = (long long)((ws_size - base) / (size_t)4000);
    R = (R / 2048) * 2048;
    if (R > CHUNK_MAX) R = CHUNK_MAX;
    if (R < 2048) R = 2048;

    float* logits = (float*)p;

    split_w<<<dim3(K_DIM / 32, N_PAD / 32), dim3(32, 32), 0, stream>>>(Wm, Wh, Wl);

    for (int m0 = 0; m0 < M_ROWS; m0 += (int)R) {
        const int rows = (int)(((long long)(M_ROWS - m0) < R) ? (M_ROWS - m0) : R);
        const int m_tiles = rows / 256;
        gemm_mfma<<<4 * m_tiles, 512, 0, stream>>>(
            x + (size_t)m0 * K_DIM, Wh, Wl, bias, logits, m_tiles);
        row_stats<<<rows / 4, 256, 0, stream>>>(logits, ent, votes, m0);
    }
    vote_kernel<<<BATCH, NUM_TTA, 0, stream>>>(ent, votes, out);
}